// Round 2
// baseline (570.131 us; speedup 1.0000x reference)
//
#include <hip/hip_runtime.h>

#define NPTS 262144
#define DIM 64
#define KCODES 1024
#define PPT 2  // points per thread

// Prep: e2[k] = sum_d emb[k][d]^2  (stored in d_ws)
__global__ void vq_e2_kernel(const float* __restrict__ emb, float* __restrict__ e2) {
    int k = blockIdx.x * blockDim.x + threadIdx.x;
    if (k < KCODES) {
        const float4* row = reinterpret_cast<const float4*>(emb + k * DIM);
        float s = 0.f;
#pragma unroll
        for (int j = 0; j < DIM / 4; ++j) {
            float4 v = row[j];
            s = fmaf(v.x, v.x, s);
            s = fmaf(v.y, v.y, s);
            s = fmaf(v.z, v.z, s);
            s = fmaf(v.w, v.w, s);
        }
        e2[k] = s;
    }
}

// Main: PPT points per thread. x rows in registers; loop over all K codes.
// emb row address is wave-uniform + __restrict__ -> scalar (SMEM) loads.
__global__ __launch_bounds__(256, 2) void vq_argmin_kernel(
    const float* __restrict__ x, const float* __restrict__ emb,
    const float* __restrict__ e2, float* __restrict__ qout,
    float* __restrict__ iout) {
    const int t = blockIdx.x * blockDim.x + threadIdx.x;
    const size_t p0 = (size_t)t * PPT;

    // Load PPT x-rows into registers (fully unrolled -> static indexing).
    float xr[PPT][DIM];
#pragma unroll
    for (int pp = 0; pp < PPT; ++pp) {
        const float4* xrow = reinterpret_cast<const float4*>(x + (p0 + pp) * DIM);
#pragma unroll
        for (int j = 0; j < DIM / 4; ++j) {
            float4 v = xrow[j];
            xr[pp][4 * j + 0] = v.x;
            xr[pp][4 * j + 1] = v.y;
            xr[pp][4 * j + 2] = v.z;
            xr[pp][4 * j + 3] = v.w;
        }
    }

    float best[PPT];
    int bidx[PPT];
#pragma unroll
    for (int pp = 0; pp < PPT; ++pp) { best[pp] = 3.4e38f; bidx[pp] = 0; }

    for (int k = 0; k < KCODES; ++k) {
        const float4* erow = reinterpret_cast<const float4*>(emb + k * DIM);
        // 4 sub-accumulators per point: break fmac dependence chains.
        float a[PPT][4];
#pragma unroll
        for (int pp = 0; pp < PPT; ++pp)
#pragma unroll
            for (int q = 0; q < 4; ++q) a[pp][q] = 0.f;

#pragma unroll
        for (int j = 0; j < DIM / 4; ++j) {
            float4 ev = erow[j];  // wave-uniform -> s_load candidate
#pragma unroll
            for (int pp = 0; pp < PPT; ++pp) {
                a[pp][0] = fmaf(xr[pp][4 * j + 0], ev.x, a[pp][0]);
                a[pp][1] = fmaf(xr[pp][4 * j + 1], ev.y, a[pp][1]);
                a[pp][2] = fmaf(xr[pp][4 * j + 2], ev.z, a[pp][2]);
                a[pp][3] = fmaf(xr[pp][4 * j + 3], ev.w, a[pp][3]);
            }
        }
        const float e2k = e2[k];
#pragma unroll
        for (int pp = 0; pp < PPT; ++pp) {
            float dot = (a[pp][0] + a[pp][1]) + (a[pp][2] + a[pp][3]);
            // argmin of x2+e2-2*dot == argmin of e2-2*dot (x2 const; sqrt monotone)
            float score = fmaf(-2.f, dot, e2k);
            // strict < + ascending k => first-index tie-break (matches jnp.argmin)
            if (score < best[pp]) { best[pp] = score; bidx[pp] = k; }
        }
    }

#pragma unroll
    for (int pp = 0; pp < PPT; ++pp) {
        const float4* qrow = reinterpret_cast<const float4*>(emb + (size_t)bidx[pp] * DIM);
        float4* orow = reinterpret_cast<float4*>(qout + (p0 + pp) * DIM);
#pragma unroll
        for (int j = 0; j < DIM / 4; ++j) orow[j] = qrow[j];
        iout[p0 + pp] = (float)bidx[pp];
    }
}

extern "C" void kernel_launch(void* const* d_in, const int* in_sizes, int n_in,
                              void* d_out, int out_size, void* d_ws, size_t ws_size,
                              hipStream_t stream) {
    const float* x = (const float*)d_in[0];    // [N, D] f32
    const float* emb = (const float*)d_in[1];  // [K, D] f32
    float* qout = (float*)d_out;               // [N, D] f32
    float* iout = (float*)d_out + (size_t)NPTS * DIM;  // [N] indices (as float)
    float* e2 = (float*)d_ws;                  // [K] f32 scratch

    vq_e2_kernel<<<(KCODES + 255) / 256, 256, 0, stream>>>(emb, e2);
    vq_argmin_kernel<<<NPTS / (256 * PPT), 256, 0, stream>>>(x, emb, e2, qout, iout);
}